// Round 2
// baseline (1753.084 us; speedup 1.0000x reference)
//
#include <hip/hip_runtime.h>
#include <cstdint>
#include <cstddef>

#define NROWS 65536
#define DIM   256
#define KCB   1024
#define NSTG  3
#define MB    32              // rows per block
#define DB    4               // d-rows staged per chunk (x 1024 codes)
#define CTS   1028            // ct row stride in floats (pad 4)
#define RST   260             // r row stride in floats (pad 4)
#define NCH   (NSTG * 64)     // total chunks: 3 stages * 64 d-chunks

// 8-wide FMA into one accumulator row (components x..w of CA/CB are 4 codes each)
#define FMA8(RV, CA, CB, ACC) do {                                    \
    (ACC)[0] = fmaf((RV), (CA).x, (ACC)[0]);                          \
    (ACC)[1] = fmaf((RV), (CA).y, (ACC)[1]);                          \
    (ACC)[2] = fmaf((RV), (CA).z, (ACC)[2]);                          \
    (ACC)[3] = fmaf((RV), (CA).w, (ACC)[3]);                          \
    (ACC)[4] = fmaf((RV), (CB).x, (ACC)[4]);                          \
    (ACC)[5] = fmaf((RV), (CB).y, (ACC)[5]);                          \
    (ACC)[6] = fmaf((RV), (CB).z, (ACC)[6]);                          \
    (ACC)[7] = fmaf((RV), (CB).w, (ACC)[7]); } while (0)

// ---------------- codebook row squared norms: c2[row] = sum(cb[row]^2) ----------------
__global__ void c2_kernel(const float* __restrict__ cb, float* __restrict__ c2) {
    int row  = blockIdx.x * 4 + (threadIdx.x >> 6);   // one wave per codebook row
    int lane = threadIdx.x & 63;
    float4 v = ((const float4*)(cb + (size_t)row * DIM))[lane];
    float s = v.x * v.x + v.y * v.y + v.z * v.z + v.w * v.w;
#pragma unroll
    for (int m = 32; m >= 1; m >>= 1) s += __shfl_xor(s, m, 64);
    if (lane == 0) c2[row] = s;
}

// ---------------- fused 3-stage residual VQ ----------------
// Geometry: 4 waves in a 2x2 grid. wy = ty>>1 owns rows [16wy,16wy+16);
// wx = ty&1 owns codes [512wx,512wx+512); lane tx owns codes
// {cbase..cbase+3} and {cbase+256..cbase+259} with cbase = 512wx + 4tx.
// Each wave reads only ITS half of the staged ct chunk (halves LDS read BW).
// r columns are stored XOR-swizzled: phys = col ^ (((col>>5)&7)<<2), row stride 260.
__global__ __launch_bounds__(256, 2)
void rvq_kernel(const float* __restrict__ z, const float* __restrict__ cb,
                const float* __restrict__ c2g, float* __restrict__ out,
                float* __restrict__ loss_acc) {
    __shared__ __align__(16) float r[MB * RST];        // 33280 B residual tile
    __shared__ __align__(16) float ct[2][DB][CTS];     // 32896 B dbuf codebook chunk [d][code]
    __shared__ __align__(16) float c2s[KCB];           // 4 KB per-stage code norms
    __shared__ float l2s[MB];
    __shared__ int   bestk[MB];
    __shared__ unsigned long long wpart[4][16];        // per-wave per-row argmin partials
    __shared__ float redw[4];

    const int tid = threadIdx.x;
    const int tx  = tid & 63;          // lane within wave
    const int ty  = tid >> 6;          // wave id
    const int wy  = ty >> 1;           // row-group: rows 16wy..16wy+15
    const int wx  = ty & 1;            // code-group: codes 512wx..512wx+511
    const int cbase = wx * 512 + tx * 4;
    const size_t rowbase = (size_t)blockIdx.x * MB;

    // ---- prologue prefetch of chunk 0 (stage 0, d 0..3): codes {tid, +256, +512, +768} ----
    float4 pv[4];
#pragma unroll
    for (int j = 0; j < 4; ++j)
        pv[j] = *(const float4*)(cb + (size_t)(j * 256 + tid) * DIM);

    // swizzled column for the linear z-load / output mapping (col = 4*(tid&63))
    const int zp = ((tid & 63) * 4) ^ (((tid & 63) >> 3) << 2);

    // ---- load z tile (coalesced float4) into swizzled r ----
    {
        const float4* zv = (const float4*)(z + rowbase * DIM);
#pragma unroll
        for (int i = 0; i < 8; ++i) {
            float4 v = zv[i * 256 + tid];
            int row = i * 4 + (tid >> 6);
            *(float4*)&r[row * RST + zp] = v;
        }
    }
    __syncthreads();

    // ---- initial per-row l2 = sum(z^2) (same math/order as before) ----
    {
        int row = tid >> 3, ch = tid & 7;
        float s = 0.f;
#pragma unroll
        for (int m = 0; m < 8; ++m) {
            float4 v = *(const float4*)&r[row * RST + ch * 32 + 4 * (m ^ ch)];
            s += v.x * v.x + v.y * v.y + v.z * v.z + v.w * v.w;
        }
        s += __shfl_xor(s, 1, 8);
        s += __shfl_xor(s, 2, 8);
        s += __shfl_xor(s, 4, 8);
        if (ch == 0) l2s[row] = s;
    }

    float4 q[8] = {};                  // straight-through accumulator (32 elems/thread)
    float lossp = 0.f;

#pragma unroll 1
    for (int stage = 0; stage < NSTG; ++stage) {
        __syncthreads();               // old c2s/l2s readers done before overwrite
        *(float4*)&c2s[tid * 4] = *(const float4*)&c2g[stage * KCB + tid * 4];

        float acc[16][8] = {};

#pragma unroll 1
        for (int di = 0; di < 64; ++di) {
            const int c = stage * 64 + di;
            // ---- stage prefetched chunk into ct[c&1] (transpose: [d][code]) ----
            {
                float* b = &ct[c & 1][0][0];
#pragma unroll
                for (int j = 0; j < 4; ++j) {
                    int code = j * 256 + tid;
                    b[0 * CTS + code] = pv[j].x;
                    b[1 * CTS + code] = pv[j].y;
                    b[2 * CTS + code] = pv[j].z;
                    b[3 * CTS + code] = pv[j].w;
                }
            }
            __syncthreads();           // single barrier per chunk (dbuf handles WAR)
            // ---- issue next chunk's global loads AFTER the barrier ----
            if (c + 1 < NCH) {
                const int cn = c + 1;
                const int s2 = cn >> 6, d2 = (cn & 63) * 4;
                const float* p = cb + (size_t)(s2 * KCB + tid) * DIM + d2;
                pv[0] = *(const float4*)p;
                pv[1] = *(const float4*)(p + 256 * DIM);
                pv[2] = *(const float4*)(p + 512 * DIM);
                pv[3] = *(const float4*)(p + 768 * DIM);
            }
            // ---- 16x8 register micro-GEMM over this 4-deep d-chunk ----
            {
                const float (*cc)[CTS] = ct[c & 1];
                const int d0 = di * 4;
                const int pc = d0 ^ (((d0 >> 5) & 7) << 2);
                float4 ca0 = *(const float4*)&cc[0][cbase];
                float4 cb0 = *(const float4*)&cc[0][cbase + 256];
                float4 ca1 = *(const float4*)&cc[1][cbase];
                float4 cb1 = *(const float4*)&cc[1][cbase + 256];
                float4 ca2 = *(const float4*)&cc[2][cbase];
                float4 cb2 = *(const float4*)&cc[2][cbase + 256];
                float4 ca3 = *(const float4*)&cc[3][cbase];
                float4 cb3 = *(const float4*)&cc[3][cbase + 256];
                const float* rbase = &r[(wy * 16) * RST + pc];
#pragma unroll
                for (int i = 0; i < 16; ++i) {
                    float4 rf = *(const float4*)(rbase + i * RST);   // wave-uniform: broadcast
                    FMA8(rf.x, ca0, cb0, acc[i]);
                    FMA8(rf.y, ca1, cb1, acc[i]);
                    FMA8(rf.z, ca2, cb2, acc[i]);
                    FMA8(rf.w, ca3, cb3, acc[i]);
                }
            }
        }

        // ---- finalize distances (np-rounding-exact) + per-wave argmin partials ----
        {
            float4 c2a = *(const float4*)&c2s[cbase];
            float4 c2b = *(const float4*)&c2s[cbase + 256];
#pragma unroll
            for (int i = 0; i < 16; ++i) {
                float l2v = l2s[wy * 16 + i];
                unsigned long long key = ~0ull;
#define KEYMIN(AJ, CJ, IDX) do {                                               \
    float dist_ = __fadd_rn(__fsub_rn(l2v, __fmul_rn(2.0f, (AJ))), (CJ));      \
    unsigned long long kk_ =                                                   \
        ((unsigned long long)__float_as_uint(dist_) << 32) | (unsigned)(IDX);  \
    key = key < kk_ ? key : kk_; } while (0)
                KEYMIN(acc[i][0], c2a.x, cbase + 0);
                KEYMIN(acc[i][1], c2a.y, cbase + 1);
                KEYMIN(acc[i][2], c2a.z, cbase + 2);
                KEYMIN(acc[i][3], c2a.w, cbase + 3);
                KEYMIN(acc[i][4], c2b.x, cbase + 256);
                KEYMIN(acc[i][5], c2b.y, cbase + 257);
                KEYMIN(acc[i][6], c2b.z, cbase + 258);
                KEYMIN(acc[i][7], c2b.w, cbase + 259);
#undef KEYMIN
#pragma unroll
                for (int m = 1; m < 64; m <<= 1) {
                    unsigned long long o = __shfl_xor(key, m, 64);
                    key = key < o ? key : o;
                }
                if (tx == 0) wpart[ty][i] = key;
            }
        }
        __syncthreads();
        // combine the two code-halves per row (ties -> lowest k via packed key)
        if (tid < 32) {
            int rwy = tid >> 4, i = tid & 15;
            unsigned long long a = wpart[rwy * 2 + 0][i];
            unsigned long long b = wpart[rwy * 2 + 1][i];
            a = a < b ? a : b;
            bestk[tid] = (int)(a & 0xffffffffu);
        }
        __syncthreads();

        // ---- phase B: straight-through update, loss, next-stage l2 (verbatim) ----
        {
            int row = tid >> 3, ch = tid & 7;
            int bk = bestk[row];
            const float4* crow = (const float4*)(cb + ((size_t)stage * KCB + bk) * DIM + ch * 32);
            float* rrow = &r[row * RST];
            float l2p = 0.f;
#pragma unroll
            for (int m = 0; m < 8; ++m) {
                int pcol = ch * 32 + 4 * (m ^ ch);
                float4 rv = *(const float4*)(rrow + pcol);
                float4 cv = crow[m];
                float t0 = __fsub_rn(cv.x, rv.x);
                float t1 = __fsub_rn(cv.y, rv.y);
                float t2 = __fsub_rn(cv.z, rv.z);
                float t3 = __fsub_rn(cv.w, rv.w);
                float s0 = __fadd_rn(rv.x, t0);
                float s1 = __fadd_rn(rv.y, t1);
                float s2 = __fadd_rn(rv.z, t2);
                float s3 = __fadd_rn(rv.w, t3);
                lossp += t0 * t0 + t1 * t1 + t2 * t2 + t3 * t3;
                if (stage == 0) {
                    q[m] = make_float4(s0, s1, s2, s3);
                } else {
                    q[m].x = __fadd_rn(q[m].x, s0);
                    q[m].y = __fadd_rn(q[m].y, s1);
                    q[m].z = __fadd_rn(q[m].z, s2);
                    q[m].w = __fadd_rn(q[m].w, s3);
                }
                if (stage < NSTG - 1) {
                    float n0 = __fsub_rn(rv.x, s0);
                    float n1 = __fsub_rn(rv.y, s1);
                    float n2 = __fsub_rn(rv.z, s2);
                    float n3 = __fsub_rn(rv.w, s3);
                    l2p += n0 * n0 + n1 * n1 + n2 * n2 + n3 * n3;
                    *(float4*)(rrow + pcol) = make_float4(n0, n1, n2, n3);
                } else {
                    *(float4*)(rrow + pcol) = q[m];   // park q for coalesced store
                }
            }
            if (stage < NSTG - 1) {
                l2p += __shfl_xor(l2p, 1, 8);
                l2p += __shfl_xor(l2p, 2, 8);
                l2p += __shfl_xor(l2p, 4, 8);
                if (ch == 0) l2s[row] = l2p;
            }
        }
    }

    __syncthreads();
    // ---- coalesced output write ----
    {
        float4* ov = (float4*)(out + rowbase * DIM);
#pragma unroll
        for (int i = 0; i < 8; ++i) {
            int row = i * 4 + (tid >> 6);
            ov[i * 256 + tid] = *(const float4*)&r[row * RST + zp];
        }
    }

    // ---- loss reduction: wave shuffle -> block -> one atomic ----
    float v = lossp;
#pragma unroll
    for (int m = 32; m >= 1; m >>= 1) v += __shfl_xor(v, m, 64);
    if ((tid & 63) == 0) redw[tid >> 6] = v;
    __syncthreads();
    if (tid == 0) atomicAdd(loss_acc, redw[0] + redw[1] + redw[2] + redw[3]);
}

// ---------------- finalize scalars ----------------
__global__ void fin_kernel(const float* __restrict__ loss_acc, float* __restrict__ out) {
    if (threadIdx.x == 0) {
        float m = loss_acc[0] / (float)((size_t)NROWS * DIM);
        out[(size_t)NROWS * DIM + 0] = m;   // codebook_loss
        out[(size_t)NROWS * DIM + 1] = m;   // commitment_loss (== forward value)
    }
}

extern "C" void kernel_launch(void* const* d_in, const int* in_sizes, int n_in,
                              void* d_out, int out_size, void* d_ws, size_t ws_size,
                              hipStream_t stream) {
    const float* z  = (const float*)d_in[0];
    const float* cb = (const float*)d_in[1];
    float* out = (float*)d_out;
    float* ws  = (float*)d_ws;
    float* c2  = ws + 16;                       // 3*1024 floats at byte offset 64

    hipMemsetAsync(ws, 0, 64, stream);          // zero the loss accumulator
    hipLaunchKernelGGL(c2_kernel, dim3(NSTG * KCB / 4), dim3(256), 0, stream, cb, c2);
    hipLaunchKernelGGL(rvq_kernel, dim3(NROWS / MB), dim3(256), 0, stream,
                       z, cb, c2, out, ws);
    hipLaunchKernelGGL(fin_kernel, dim3(1), dim3(64), 0, stream, ws, out);
}

// Round 3
// 1626.137 us; speedup vs baseline: 1.0781x; 1.0781x over previous
//
#include <hip/hip_runtime.h>
#include <cstdint>
#include <cstddef>

#define NROWS 65536
#define DIM   256
#define KCB   1024
#define NSTG  3
#define MB    32              // rows per block
#define DB    8               // d-rows staged per chunk (x 1024 codes)
#define RST   260             // r row stride in floats (pad 4)
#define NCH   (NSTG * 32)     // total chunks: 3 stages * 32 d-chunks

// compile-time float4 component select (C must be a literal after unroll)
#define RCOMP(V, C) ((C) == 0 ? (V).x : (C) == 1 ? (V).y : (C) == 2 ? (V).z : (V).w)

// 8-wide FMA into one accumulator row (components x..w of CA/CB are 4 codes each)
#define FMA8(RV, CA, CB, ACC) do {                                    \
    (ACC)[0] = fmaf((RV), (CA).x, (ACC)[0]);                          \
    (ACC)[1] = fmaf((RV), (CA).y, (ACC)[1]);                          \
    (ACC)[2] = fmaf((RV), (CA).z, (ACC)[2]);                          \
    (ACC)[3] = fmaf((RV), (CA).w, (ACC)[3]);                          \
    (ACC)[4] = fmaf((RV), (CB).x, (ACC)[4]);                          \
    (ACC)[5] = fmaf((RV), (CB).y, (ACC)[5]);                          \
    (ACC)[6] = fmaf((RV), (CB).z, (ACC)[6]);                          \
    (ACC)[7] = fmaf((RV), (CB).w, (ACC)[7]); } while (0)

// ---------------- codebook row squared norms: c2[row] = sum(cb[row]^2) ----------------
__global__ void c2_kernel(const float* __restrict__ cb, float* __restrict__ c2) {
    int row  = blockIdx.x * 4 + (threadIdx.x >> 6);   // one wave per codebook row
    int lane = threadIdx.x & 63;
    float4 v = ((const float4*)(cb + (size_t)row * DIM))[lane];
    float s = v.x * v.x + v.y * v.y + v.z * v.z + v.w * v.w;
#pragma unroll
    for (int m = 32; m >= 1; m >>= 1) s += __shfl_xor(s, m, 64);
    if (lane == 0) c2[row] = s;
}

// ---------------- fused 3-stage residual VQ ----------------
// 512 threads = 8 waves in a 4x2 grid: wy = ty>>1 owns rows [8wy,8wy+8);
// wx = ty&1 owns codes [512wx,512wx+512); lane tx owns codes
// {cbase..cbase+3} and {cbase+256..cbase+259}, cbase = 512wx + 4tx.
// r rows (residuals) live BOTH in LDS (phase B, exactness-critical, tid<256 only)
// and in wave registers (rreg: lane tx holds r[row][4tx..4tx+3]); the GEMM's
// r-operand broadcast uses v_readlane (VALU) instead of LDS reads.
// r columns are XOR-swizzled: phys = col ^ (((col>>5)&7)<<2), row stride 260.
__global__ __launch_bounds__(512, 2)
void rvq_kernel(const float* __restrict__ z, const float* __restrict__ cb,
                const float* __restrict__ c2g, float* __restrict__ out,
                float* __restrict__ loss_acc) {
    __shared__ __align__(16) float r[MB * RST];        // 33280 B residual tile
    __shared__ __align__(16) float ct[2][DB][KCB];     // 65536 B dbuf codebook chunk [d][code]
    __shared__ __align__(16) float c2s[KCB];           // 4 KB per-stage code norms
    __shared__ float l2s[MB];
    __shared__ int   bestk[MB];
    __shared__ unsigned long long wpart[8][8];         // per-wave per-row argmin partials
    __shared__ float redw[8];

    const int tid = threadIdx.x;
    const int tx  = tid & 63;          // lane within wave
    const int ty  = tid >> 6;          // wave id 0..7
    const int wy  = ty >> 1;           // row-group: rows 8wy..8wy+7
    const int wx  = ty & 1;            // code-half: codes 512wx..512wx+511
    const int wr0 = wy * 8;
    const int cbase = wx * 512 + tx * 4;
    const int rp = (tx * 4) ^ ((tx >> 3) << 2);        // swizzled offset of col 4*tx
    const size_t rowbase = (size_t)blockIdx.x * MB;

    // ---- prologue prefetch of chunk 0 (stage 0, d 0..7): codes {tid, tid+512} ----
    float4 pv[4];
    {
        const float* p0 = cb + (size_t)tid * DIM;
        const float* p1 = cb + (size_t)(tid + 512) * DIM;
        pv[0] = ((const float4*)p0)[0];
        pv[1] = ((const float4*)p0)[1];
        pv[2] = ((const float4*)p1)[0];
        pv[3] = ((const float4*)p1)[1];
    }

    // ---- load z tile (coalesced float4, all 512 threads) into swizzled r ----
    {
        const float4* zv = (const float4*)(z + rowbase * DIM);
#pragma unroll
        for (int i = 0; i < 4; ++i) {
            float4 v = zv[i * 512 + tid];
            int row = i * 8 + (tid >> 6);
            *(float4*)&r[row * RST + rp] = v;
        }
    }
    __syncthreads();

    // ---- initial per-row l2 = sum(z^2) (byte-identical reduction, tid<256) ----
    if (tid < 256) {
        int row = tid >> 3, ch = tid & 7;
        float s = 0.f;
#pragma unroll
        for (int m = 0; m < 8; ++m) {
            float4 v = *(const float4*)&r[row * RST + ch * 32 + 4 * (m ^ ch)];
            s += v.x * v.x + v.y * v.y + v.z * v.z + v.w * v.w;
        }
        s += __shfl_xor(s, 1, 8);
        s += __shfl_xor(s, 2, 8);
        s += __shfl_xor(s, 4, 8);
        if (ch == 0) l2s[row] = s;
    }

    float4 q[8] = {};                  // straight-through accumulator (tid<256 only)
    float lossp = 0.f;

#pragma unroll 1
    for (int stage = 0; stage < NSTG; ++stage) {
        __syncthreads();               // phase-B / l2 / z-load writers done
        if (tid < 256)
            *(float4*)&c2s[tid * 4] = *(const float4*)&c2g[stage * KCB + tid * 4];

        // refresh this wave's 8 residual rows into registers (lane tx: cols 4tx..4tx+3)
        float4 rreg[8];
#pragma unroll
        for (int i = 0; i < 8; ++i)
            rreg[i] = *(const float4*)&r[(wr0 + i) * RST + rp];

        float acc[8][8] = {};

#pragma unroll 1
        for (int di = 0; di < 32; ++di) {
            const int c = stage * 32 + di;
            // ---- stage prefetched chunk into ct[c&1] (transpose: [d][code]) ----
            {
                float* b = &ct[c & 1][0][0];
#pragma unroll
                for (int dd = 0; dd < 8; ++dd) {
                    b[dd * KCB + tid]       = RCOMP(pv[dd >> 2], dd & 3);
                    b[dd * KCB + tid + 512] = RCOMP(pv[2 + (dd >> 2)], dd & 3);
                }
            }
            __syncthreads();           // single barrier per chunk (dbuf handles WAR)
            // ---- issue next chunk's global loads AFTER the barrier ----
            if (c + 1 < NCH) {
                const int cn = c + 1;
                const int s2 = cn >> 5, d2 = (cn & 31) * DB;
                const float* p0 = cb + ((size_t)(s2 * KCB) + tid) * DIM + d2;
                const float* p1 = p0 + (size_t)512 * DIM;
                pv[0] = ((const float4*)p0)[0];
                pv[1] = ((const float4*)p0)[1];
                pv[2] = ((const float4*)p1)[0];
                pv[3] = ((const float4*)p1)[1];
            }
            // ---- 8x8 register micro-GEMM; r-scalar broadcast via v_readlane ----
            {
                const float (*cc)[KCB] = ct[c & 1];
#pragma unroll
                for (int dd = 0; dd < 8; ++dd) {
                    float4 ca  = *(const float4*)&cc[dd][cbase];
                    float4 cbv = *(const float4*)&cc[dd][cbase + 256];
                    int sl = di * 2 + (dd >> 2);   // source lane holding d = 8*di+dd
#pragma unroll
                    for (int i = 0; i < 8; ++i) {
                        float sr = __uint_as_float(__builtin_amdgcn_readlane(
                            __float_as_uint(RCOMP(rreg[i], dd & 3)), sl));
                        FMA8(sr, ca, cbv, acc[i]);
                    }
                }
            }
        }

        // ---- finalize distances (np-rounding-exact) + per-wave argmin partials ----
        {
            float4 c2a = *(const float4*)&c2s[cbase];
            float4 c2b = *(const float4*)&c2s[cbase + 256];
#pragma unroll
            for (int i = 0; i < 8; ++i) {
                float l2v = l2s[wr0 + i];
                unsigned long long key = ~0ull;
#define KEYMIN(AJ, CJ, IDX) do {                                               \
    float dist_ = __fadd_rn(__fsub_rn(l2v, __fmul_rn(2.0f, (AJ))), (CJ));      \
    unsigned long long kk_ =                                                   \
        ((unsigned long long)__float_as_uint(dist_) << 32) | (unsigned)(IDX);  \
    key = key < kk_ ? key : kk_; } while (0)
                KEYMIN(acc[i][0], c2a.x, cbase + 0);
                KEYMIN(acc[i][1], c2a.y, cbase + 1);
                KEYMIN(acc[i][2], c2a.z, cbase + 2);
                KEYMIN(acc[i][3], c2a.w, cbase + 3);
                KEYMIN(acc[i][4], c2b.x, cbase + 256);
                KEYMIN(acc[i][5], c2b.y, cbase + 257);
                KEYMIN(acc[i][6], c2b.z, cbase + 258);
                KEYMIN(acc[i][7], c2b.w, cbase + 259);
#undef KEYMIN
#pragma unroll
                for (int m = 1; m < 64; m <<= 1) {
                    unsigned long long o = __shfl_xor(key, m, 64);
                    key = key < o ? key : o;
                }
                if (tx == 0) wpart[ty][i] = key;
            }
        }
        __syncthreads();
        // combine the two code-halves per row (ties -> lowest k via packed key)
        if (tid < 32) {
            int wyy = tid >> 3, i = tid & 7;
            unsigned long long a = wpart[wyy * 2 + 0][i];
            unsigned long long b = wpart[wyy * 2 + 1][i];
            a = a < b ? a : b;
            bestk[tid] = (int)(a & 0xffffffffu);
        }
        __syncthreads();

        // ---- phase B: straight-through update, loss, next-stage l2 (verbatim, tid<256) ----
        if (tid < 256) {
            int row = tid >> 3, ch = tid & 7;
            int bk = bestk[row];
            const float4* crow = (const float4*)(cb + ((size_t)stage * KCB + bk) * DIM + ch * 32);
            float* rrow = &r[row * RST];
            float l2p = 0.f;
#pragma unroll
            for (int m = 0; m < 8; ++m) {
                int pcol = ch * 32 + 4 * (m ^ ch);
                float4 rv = *(const float4*)(rrow + pcol);
                float4 cv = crow[m];
                float t0 = __fsub_rn(cv.x, rv.x);
                float t1 = __fsub_rn(cv.y, rv.y);
                float t2 = __fsub_rn(cv.z, rv.z);
                float t3 = __fsub_rn(cv.w, rv.w);
                float s0 = __fadd_rn(rv.x, t0);
                float s1 = __fadd_rn(rv.y, t1);
                float s2 = __fadd_rn(rv.z, t2);
                float s3 = __fadd_rn(rv.w, t3);
                lossp += t0 * t0 + t1 * t1 + t2 * t2 + t3 * t3;
                if (stage == 0) {
                    q[m] = make_float4(s0, s1, s2, s3);
                } else {
                    q[m].x = __fadd_rn(q[m].x, s0);
                    q[m].y = __fadd_rn(q[m].y, s1);
                    q[m].z = __fadd_rn(q[m].z, s2);
                    q[m].w = __fadd_rn(q[m].w, s3);
                }
                if (stage < NSTG - 1) {
                    float n0 = __fsub_rn(rv.x, s0);
                    float n1 = __fsub_rn(rv.y, s1);
                    float n2 = __fsub_rn(rv.z, s2);
                    float n3 = __fsub_rn(rv.w, s3);
                    l2p += n0 * n0 + n1 * n1 + n2 * n2 + n3 * n3;
                    *(float4*)(rrow + pcol) = make_float4(n0, n1, n2, n3);
                } else {
                    *(float4*)(rrow + pcol) = q[m];   // park q for coalesced store
                }
            }
            if (stage < NSTG - 1) {
                l2p += __shfl_xor(l2p, 1, 8);
                l2p += __shfl_xor(l2p, 2, 8);
                l2p += __shfl_xor(l2p, 4, 8);
                if (ch == 0) l2s[row] = l2p;
            }
        }
    }

    __syncthreads();
    // ---- coalesced output write (all 512 threads) ----
    {
        float4* ov = (float4*)(out + rowbase * DIM);
#pragma unroll
        for (int i = 0; i < 4; ++i) {
            int row = i * 8 + (tid >> 6);
            ov[i * 512 + tid] = *(const float4*)&r[row * RST + rp];
        }
    }

    // ---- loss reduction: wave shuffle -> block -> one atomic ----
    float v = lossp;
#pragma unroll
    for (int m = 32; m >= 1; m >>= 1) v += __shfl_xor(v, m, 64);
    if ((tid & 63) == 0) redw[ty] = v;
    __syncthreads();
    if (tid == 0) {
        float s = redw[0] + redw[1] + redw[2] + redw[3];   // waves 4..7 contribute exact 0.0f
        s = s + redw[4] + redw[5] + redw[6] + redw[7];
        atomicAdd(loss_acc, s);
    }
}

// ---------------- finalize scalars ----------------
__global__ void fin_kernel(const float* __restrict__ loss_acc, float* __restrict__ out) {
    if (threadIdx.x == 0) {
        float m = loss_acc[0] / (float)((size_t)NROWS * DIM);
        out[(size_t)NROWS * DIM + 0] = m;   // codebook_loss
        out[(size_t)NROWS * DIM + 1] = m;   // commitment_loss (== forward value)
    }
}

extern "C" void kernel_launch(void* const* d_in, const int* in_sizes, int n_in,
                              void* d_out, int out_size, void* d_ws, size_t ws_size,
                              hipStream_t stream) {
    const float* z  = (const float*)d_in[0];
    const float* cb = (const float*)d_in[1];
    float* out = (float*)d_out;
    float* ws  = (float*)d_ws;
    float* c2  = ws + 16;                       // 3*1024 floats at byte offset 64

    hipMemsetAsync(ws, 0, 64, stream);          // zero the loss accumulator
    hipLaunchKernelGGL(c2_kernel, dim3(NSTG * KCB / 4), dim3(256), 0, stream, cb, c2);
    hipLaunchKernelGGL(rvq_kernel, dim3(NROWS / MB), dim3(512), 0, stream,
                       z, cb, c2, out, ws);
    hipLaunchKernelGGL(fin_kernel, dim3(1), dim3(64), 0, stream, ws, out);
}

// Round 4
// 1564.244 us; speedup vs baseline: 1.1207x; 1.0396x over previous
//
#include <hip/hip_runtime.h>
#include <cstdint>
#include <cstddef>

#define NROWS 65536
#define DIM   256
#define KCB   1024
#define NSTG  3
#define MB    32              // rows per block
#define DB    8               // d-rows staged per chunk (x 1024 codes)
#define RST   260             // r row stride in floats (pad 4)
#define NCH   (NSTG * 32)     // total chunks: 3 stages * 32 d-chunks

// compile-time float4 component select (C must be a literal after unroll)
#define RCOMP(V, C) ((C) == 0 ? (V).x : (C) == 1 ? (V).y : (C) == 2 ? (V).z : (V).w)

// 8-wide FMA into one accumulator row (components x..w of CA/CB are 4 codes each)
#define FMA8(RV, CA, CB, ACC) do {                                    \
    (ACC)[0] = fmaf((RV), (CA).x, (ACC)[0]);                          \
    (ACC)[1] = fmaf((RV), (CA).y, (ACC)[1]);                          \
    (ACC)[2] = fmaf((RV), (CA).z, (ACC)[2]);                          \
    (ACC)[3] = fmaf((RV), (CA).w, (ACC)[3]);                          \
    (ACC)[4] = fmaf((RV), (CB).x, (ACC)[4]);                          \
    (ACC)[5] = fmaf((RV), (CB).y, (ACC)[5]);                          \
    (ACC)[6] = fmaf((RV), (CB).z, (ACC)[6]);                          \
    (ACC)[7] = fmaf((RV), (CB).w, (ACC)[7]); } while (0)

// prefetch chunk CN (clamped in-bounds) into register set DST
#define PREFETCH(CN, DST) do {                                        \
    int cn_ = (CN) < NCH - 1 ? (CN) : NCH - 1;                        \
    const int s2_ = cn_ >> 5, d2_ = (cn_ & 31) * DB;                  \
    const float* p0_ = cb + ((size_t)(s2_ * KCB) + tid) * DIM + d2_;  \
    const float* p1_ = p0_ + (size_t)512 * DIM;                       \
    DST[0] = ((const float4*)p0_)[0];                                 \
    DST[1] = ((const float4*)p0_)[1];                                 \
    DST[2] = ((const float4*)p1_)[0];                                 \
    DST[3] = ((const float4*)p1_)[1]; } while (0)

// one chunk: compute ct-buffer RB, stage SRC regs into WB, r-broadcast lane base SLB
#define CHUNK(RB, WB, SRC, SLB) do {                                  \
    const float (*cc_)[KCB] = (RB);                                   \
    float* nb_ = &(WB)[0][0];                                         \
    _Pragma("unroll")                                                 \
    for (int dd = 0; dd < 8; ++dd) {                                  \
        float4 ca_  = *(const float4*)&cc_[dd][cbase];                \
        float4 cbv_ = *(const float4*)&cc_[dd][cbase + 256];          \
        nb_[dd * KCB + tid]       = RCOMP(SRC[dd >> 2], dd & 3);      \
        nb_[dd * KCB + tid + 512] = RCOMP(SRC[2 + (dd >> 2)], dd & 3);\
        int sl_ = (SLB) + (dd >> 2);                                  \
        _Pragma("unroll")                                             \
        for (int i = 0; i < 8; ++i) {                                 \
            float sr_ = __uint_as_float(__builtin_amdgcn_readlane(    \
                __float_as_uint(RCOMP(rreg[i], dd & 3)), sl_));       \
            FMA8(sr_, ca_, cbv_, acc[i]);                             \
        }                                                             \
    } } while (0)

// ---------------- codebook row squared norms: c2[row] = sum(cb[row]^2) ----------------
__global__ void c2_kernel(const float* __restrict__ cb, float* __restrict__ c2) {
    int row  = blockIdx.x * 4 + (threadIdx.x >> 6);   // one wave per codebook row
    int lane = threadIdx.x & 63;
    float4 v = ((const float4*)(cb + (size_t)row * DIM))[lane];
    float s = v.x * v.x + v.y * v.y + v.z * v.z + v.w * v.w;
#pragma unroll
    for (int m = 32; m >= 1; m >>= 1) s += __shfl_xor(s, m, 64);
    if (lane == 0) c2[row] = s;
}

// ---------------- fused 3-stage residual VQ ----------------
// 512 threads = 8 waves in a 4x2 grid: wy = ty>>1 owns rows [8wy,8wy+8);
// wx = ty&1 owns codes [512wx,512wx+512); lane tx owns codes
// {cbase..cbase+3} and {cbase+256..cbase+259}, cbase = 512wx + 4tx.
// Software pipeline: iter c computes ct[c&1] while staging chunk c+1 (regs,
// static ping-pong pvA/pvB) into ct[(c+1)&1] and prefetching chunk c+2.
// One barrier per chunk, at the end. r-broadcasts via v_readlane (no LDS).
// waves_per_eu(2,2): LDS (103.7 KB) caps us at 1 block/CU = 2 waves/EU anyway;
// pinning max occupancy lets the allocator use 256 VGPRs (R3's 128-cap put
// acc[8][8] into AGPRs with accvgpr churn).
__global__ __attribute__((amdgpu_flat_work_group_size(512, 512)))
__attribute__((amdgpu_waves_per_eu(2, 2)))
void rvq_kernel(const float* __restrict__ z, const float* __restrict__ cb,
                const float* __restrict__ c2g, float* __restrict__ out,
                float* __restrict__ loss_acc) {
    __shared__ __align__(16) float r[MB * RST];        // 33280 B residual tile
    __shared__ __align__(16) float ct[2][DB][KCB];     // 65536 B dbuf codebook chunk [d][code]
    __shared__ __align__(16) float c2s[KCB];           // 4 KB per-stage code norms
    __shared__ float l2s[MB];
    __shared__ int   bestk[MB];
    __shared__ unsigned long long wpart[8][8];         // per-wave per-row argmin partials
    __shared__ float redw[8];

    const int tid = threadIdx.x;
    const int tx  = tid & 63;          // lane within wave
    const int ty  = tid >> 6;          // wave id 0..7
    const int wy  = ty >> 1;           // row-group: rows 8wy..8wy+7
    const int wx  = ty & 1;            // code-half: codes 512wx..512wx+511
    const int wr0 = wy * 8;
    const int cbase = wx * 512 + tx * 4;
    const int rp = (tx * 4) ^ ((tx >> 3) << 2);        // swizzled offset of col 4*tx
    const size_t rowbase = (size_t)blockIdx.x * MB;

    float4 pvA[4], pvB[4];             // ping-pong staging registers

    // ---- prologue: chunk 0 -> A ----
    PREFETCH(0, pvA);

    // ---- load z tile (coalesced float4, all 512 threads) into swizzled r ----
    {
        const float4* zv = (const float4*)(z + rowbase * DIM);
#pragma unroll
        for (int i = 0; i < 4; ++i) {
            float4 v = zv[i * 512 + tid];
            int row = i * 8 + (tid >> 6);
            *(float4*)&r[row * RST + rp] = v;
        }
    }

    // ---- stage chunk 0 -> ct[0]; then chunk 1 -> B ----
    {
        float* b = &ct[0][0][0];
#pragma unroll
        for (int dd = 0; dd < 8; ++dd) {
            b[dd * KCB + tid]       = RCOMP(pvA[dd >> 2], dd & 3);
            b[dd * KCB + tid + 512] = RCOMP(pvA[2 + (dd >> 2)], dd & 3);
        }
    }
    PREFETCH(1, pvB);
    __syncthreads();                   // r + ct[0] ready

    // ---- initial per-row l2 = sum(z^2) (byte-identical reduction, tid<256) ----
    if (tid < 256) {
        int row = tid >> 3, ch = tid & 7;
        float s = 0.f;
#pragma unroll
        for (int m = 0; m < 8; ++m) {
            float4 v = *(const float4*)&r[row * RST + ch * 32 + 4 * (m ^ ch)];
            s += v.x * v.x + v.y * v.y + v.z * v.z + v.w * v.w;
        }
        s += __shfl_xor(s, 1, 8);
        s += __shfl_xor(s, 2, 8);
        s += __shfl_xor(s, 4, 8);
        if (ch == 0) l2s[row] = s;
    }

    float4 q[8] = {};                  // straight-through accumulator (tid<256 only)
    float lossp = 0.f;

#pragma unroll 1
    for (int stage = 0; stage < NSTG; ++stage) {
        __syncthreads();               // phase-B / l2 / z-load writers done
        if (tid < 256)
            *(float4*)&c2s[tid * 4] = *(const float4*)&c2g[stage * KCB + tid * 4];

        // refresh this wave's 8 residual rows into registers (lane tx: cols 4tx..4tx+3)
        float4 rreg[8];
#pragma unroll
        for (int i = 0; i < 8; ++i)
            rreg[i] = *(const float4*)&r[(wr0 + i) * RST + rp];

        float acc[8][8] = {};

#pragma unroll 1
        for (int di2 = 0; di2 < 16; ++di2) {
            const int c0 = stage * 32 + di2 * 2;
            // -- even chunk c0: compute ct[0], stage c0+1 from B -> ct[1], prefetch c0+2 -> A
            PREFETCH(c0 + 2, pvA);
            CHUNK(ct[0], ct[1], pvB, di2 * 4);
            __syncthreads();
            // -- odd chunk c0+1: compute ct[1], stage c0+2 from A -> ct[0], prefetch c0+3 -> B
            PREFETCH(c0 + 3, pvB);
            CHUNK(ct[1], ct[0], pvA, di2 * 4 + 2);
            __syncthreads();
        }

        // ---- finalize distances (np-rounding-exact) + per-wave argmin partials ----
        {
            float4 c2a = *(const float4*)&c2s[cbase];
            float4 c2b = *(const float4*)&c2s[cbase + 256];
#pragma unroll
            for (int i = 0; i < 8; ++i) {
                float l2v = l2s[wr0 + i];
                unsigned long long key = ~0ull;
#define KEYMIN(AJ, CJ, IDX) do {                                               \
    float dist_ = __fadd_rn(__fsub_rn(l2v, __fmul_rn(2.0f, (AJ))), (CJ));      \
    unsigned long long kk_ =                                                   \
        ((unsigned long long)__float_as_uint(dist_) << 32) | (unsigned)(IDX);  \
    key = key < kk_ ? key : kk_; } while (0)
                KEYMIN(acc[i][0], c2a.x, cbase + 0);
                KEYMIN(acc[i][1], c2a.y, cbase + 1);
                KEYMIN(acc[i][2], c2a.z, cbase + 2);
                KEYMIN(acc[i][3], c2a.w, cbase + 3);
                KEYMIN(acc[i][4], c2b.x, cbase + 256);
                KEYMIN(acc[i][5], c2b.y, cbase + 257);
                KEYMIN(acc[i][6], c2b.z, cbase + 258);
                KEYMIN(acc[i][7], c2b.w, cbase + 259);
#undef KEYMIN
#pragma unroll
                for (int m = 1; m < 64; m <<= 1) {
                    unsigned long long o = __shfl_xor(key, m, 64);
                    key = key < o ? key : o;
                }
                if (tx == 0) wpart[ty][i] = key;
            }
        }
        __syncthreads();
        // combine the two code-halves per row (ties -> lowest k via packed key)
        if (tid < 32) {
            int wyy = tid >> 3, i = tid & 7;
            unsigned long long a = wpart[wyy * 2 + 0][i];
            unsigned long long b = wpart[wyy * 2 + 1][i];
            a = a < b ? a : b;
            bestk[tid] = (int)(a & 0xffffffffu);
        }
        __syncthreads();

        // ---- phase B: straight-through update, loss, next-stage l2 (verbatim, tid<256) ----
        if (tid < 256) {
            int row = tid >> 3, ch = tid & 7;
            int bk = bestk[row];
            const float4* crow = (const float4*)(cb + ((size_t)stage * KCB + bk) * DIM + ch * 32);
            float* rrow = &r[row * RST];
            float l2p = 0.f;
#pragma unroll
            for (int m = 0; m < 8; ++m) {
                int pcol = ch * 32 + 4 * (m ^ ch);
                float4 rv = *(const float4*)(rrow + pcol);
                float4 cv = crow[m];
                float t0 = __fsub_rn(cv.x, rv.x);
                float t1 = __fsub_rn(cv.y, rv.y);
                float t2 = __fsub_rn(cv.z, rv.z);
                float t3 = __fsub_rn(cv.w, rv.w);
                float s0 = __fadd_rn(rv.x, t0);
                float s1 = __fadd_rn(rv.y, t1);
                float s2 = __fadd_rn(rv.z, t2);
                float s3 = __fadd_rn(rv.w, t3);
                lossp += t0 * t0 + t1 * t1 + t2 * t2 + t3 * t3;
                if (stage == 0) {
                    q[m] = make_float4(s0, s1, s2, s3);
                } else {
                    q[m].x = __fadd_rn(q[m].x, s0);
                    q[m].y = __fadd_rn(q[m].y, s1);
                    q[m].z = __fadd_rn(q[m].z, s2);
                    q[m].w = __fadd_rn(q[m].w, s3);
                }
                if (stage < NSTG - 1) {
                    float n0 = __fsub_rn(rv.x, s0);
                    float n1 = __fsub_rn(rv.y, s1);
                    float n2 = __fsub_rn(rv.z, s2);
                    float n3 = __fsub_rn(rv.w, s3);
                    l2p += n0 * n0 + n1 * n1 + n2 * n2 + n3 * n3;
                    *(float4*)(rrow + pcol) = make_float4(n0, n1, n2, n3);
                } else {
                    *(float4*)(rrow + pcol) = q[m];   // park q for coalesced store
                }
            }
            if (stage < NSTG - 1) {
                l2p += __shfl_xor(l2p, 1, 8);
                l2p += __shfl_xor(l2p, 2, 8);
                l2p += __shfl_xor(l2p, 4, 8);
                if (ch == 0) l2s[row] = l2p;
            }
        }
    }

    __syncthreads();
    // ---- coalesced output write (all 512 threads) ----
    {
        float4* ov = (float4*)(out + rowbase * DIM);
#pragma unroll
        for (int i = 0; i < 4; ++i) {
            int row = i * 8 + (tid >> 6);
            ov[i * 512 + tid] = *(const float4*)&r[row * RST + rp];
        }
    }

    // ---- loss reduction: wave shuffle -> block -> one atomic ----
    float v = lossp;
#pragma unroll
    for (int m = 32; m >= 1; m >>= 1) v += __shfl_xor(v, m, 64);
    if ((tid & 63) == 0) redw[ty] = v;
    __syncthreads();
    if (tid == 0) {
        float s = redw[0] + redw[1] + redw[2] + redw[3];   // waves 4..7 contribute exact 0.0f
        s = s + redw[4] + redw[5] + redw[6] + redw[7];
        atomicAdd(loss_acc, s);
    }
}

// ---------------- finalize scalars ----------------
__global__ void fin_kernel(const float* __restrict__ loss_acc, float* __restrict__ out) {
    if (threadIdx.x == 0) {
        float m = loss_acc[0] / (float)((size_t)NROWS * DIM);
        out[(size_t)NROWS * DIM + 0] = m;   // codebook_loss
        out[(size_t)NROWS * DIM + 1] = m;   // commitment_loss (== forward value)
    }
}

extern "C" void kernel_launch(void* const* d_in, const int* in_sizes, int n_in,
                              void* d_out, int out_size, void* d_ws, size_t ws_size,
                              hipStream_t stream) {
    const float* z  = (const float*)d_in[0];
    const float* cb = (const float*)d_in[1];
    float* out = (float*)d_out;
    float* ws  = (float*)d_ws;
    float* c2  = ws + 16;                       // 3*1024 floats at byte offset 64

    hipMemsetAsync(ws, 0, 64, stream);          // zero the loss accumulator
    hipLaunchKernelGGL(c2_kernel, dim3(NSTG * KCB / 4), dim3(256), 0, stream, cb, c2);
    hipLaunchKernelGGL(rvq_kernel, dim3(NROWS / MB), dim3(512), 0, stream,
                       z, cb, c2, out, ws);
    hipLaunchKernelGGL(fin_kernel, dim3(1), dim3(64), 0, stream, ws, out);
}